// Round 1
// baseline (315.289 us; speedup 1.0000x reference)
//
#include <hip/hip_runtime.h>
#include <math.h>

#define TPB 256
#define W 64
#define H 64
#define LDSW 68   // row stride in floats: 68*4=272 B, 16B-aligned rows, breaks pow-2 bank stride

__global__ __launch_bounds__(TPB) void spp_kernel(const float* __restrict__ in,
                                                  float* __restrict__ out) {
    __shared__ __align__(16) float s_in[H * LDSW];
    __shared__ __align__(16) float s_r5[H * LDSW];
    __shared__ __align__(16) float s_r9[H * LDSW];
    __shared__ __align__(16) float s_r13[H * LDSW];

    const int tid = threadIdx.x;
    const int bc  = blockIdx.x;                  // b*256 + c
    const int b   = bc >> 8;
    const int c   = bc & 255;
    const size_t img   = (size_t)bc * (H * W);
    const size_t obase = ((size_t)b * 1024 + c) * (H * W);
    const size_t pstr  = (size_t)256 * H * W;    // pool stride in out (channels block)
    const float NEG = -INFINITY;

    // ---- phase 1: coalesced float4 load of the image into LDS ----
    {
        const float4* in4 = (const float4*)(in + img);
        #pragma unroll
        for (int i = 0; i < 4; ++i) {
            int idx = tid + TPB * i;             // float4 index 0..1023
            int y = idx >> 4;
            int q = idx & 15;
            float4 v = in4[idx];
            *(float4*)&s_in[y * LDSW + q * 4] = v;
        }
    }
    __syncthreads();

    // ---- phase 2: row pass (r5 / r9 / r13), thread owns a 16-wide row strip ----
    {
        const int y  = tid >> 2;
        const int x0 = (tid & 3) << 4;
        float seg[32];                            // in[x0-8 .. x0+23], OOB = -inf
        #pragma unroll
        for (int j = 0; j < 8; ++j) {
            int xs = x0 - 8 + 4 * j;
            float4 v;
            if (xs >= 0 && xs < W) v = *(const float4*)&s_in[y * LDSW + xs];
            else                   v = make_float4(NEG, NEG, NEG, NEG);
            seg[4*j+0] = v.x; seg[4*j+1] = v.y; seg[4*j+2] = v.z; seg[4*j+3] = v.w;
        }
        float r5[24];                             // r5[i] = rowmax5 at x = x0-4+i
        #pragma unroll
        for (int i = 0; i < 24; ++i) {
            float m = seg[i+2];
            m = fmaxf(m, seg[i+3]); m = fmaxf(m, seg[i+4]);
            m = fmaxf(m, seg[i+5]); m = fmaxf(m, seg[i+6]);
            r5[i] = m;
        }
        float r9[16], r13[16];
        #pragma unroll
        for (int i = 0; i < 16; ++i) {
            r9[i]  = fmaxf(r5[i+2], r5[i+6]);                     // rowmax9  at x0+i
            r13[i] = fmaxf(fmaxf(r5[i], r5[i+4]), r5[i+8]);       // rowmax13 at x0+i
        }
        const int base = y * LDSW + x0;
        #pragma unroll
        for (int g = 0; g < 4; ++g) {
            *(float4*)&s_r5 [base + 4*g] = make_float4(r5[4+4*g], r5[5+4*g], r5[6+4*g], r5[7+4*g]);
            *(float4*)&s_r9 [base + 4*g] = make_float4(r9[4*g],  r9[4*g+1],  r9[4*g+2],  r9[4*g+3]);
            *(float4*)&s_r13[base + 4*g] = make_float4(r13[4*g], r13[4*g+1], r13[4*g+2], r13[4*g+3]);
        }
    }
    __syncthreads();

    // ---- phase 3: pool-0 is a straight copy of x (LDS -> global, float4) ----
    {
        float4* o4 = (float4*)(out + obase);
        #pragma unroll
        for (int i = 0; i < 4; ++i) {
            int idx = tid + TPB * i;
            int y = idx >> 4;
            int q = idx & 15;
            o4[idx] = *(const float4*)&s_in[y * LDSW + q * 4];
        }
    }

    // ---- phase 4: column pass, thread owns a 16-tall column strip ----
    {
        const int x  = tid & 63;                  // lanes span x -> conflict-free LDS col reads
        const int y0 = (tid >> 6) << 4;

        // pool 5
        {
            float cv[20];
            #pragma unroll
            for (int j = 0; j < 20; ++j) {
                int y = y0 - 2 + j;
                cv[j] = (y >= 0 && y < H) ? s_r5[y * LDSW + x] : NEG;
            }
            float* o = out + obase + pstr;
            #pragma unroll
            for (int i = 0; i < 16; ++i) {
                float m = cv[i];
                m = fmaxf(m, cv[i+1]); m = fmaxf(m, cv[i+2]);
                m = fmaxf(m, cv[i+3]); m = fmaxf(m, cv[i+4]);
                o[(y0 + i) * W + x] = m;
            }
        }
        // pool 9
        {
            float cv[24];
            #pragma unroll
            for (int j = 0; j < 24; ++j) {
                int y = y0 - 4 + j;
                cv[j] = (y >= 0 && y < H) ? s_r9[y * LDSW + x] : NEG;
            }
            float* o = out + obase + 2 * pstr;
            #pragma unroll
            for (int i = 0; i < 16; ++i) {
                float m = cv[i];
                #pragma unroll
                for (int d = 1; d < 9; ++d) m = fmaxf(m, cv[i+d]);
                o[(y0 + i) * W + x] = m;
            }
        }
        // pool 13
        {
            float cv[28];
            #pragma unroll
            for (int j = 0; j < 28; ++j) {
                int y = y0 - 6 + j;
                cv[j] = (y >= 0 && y < H) ? s_r13[y * LDSW + x] : NEG;
            }
            float* o = out + obase + 3 * pstr;
            #pragma unroll
            for (int i = 0; i < 16; ++i) {
                float m = cv[i];
                #pragma unroll
                for (int d = 1; d < 13; ++d) m = fmaxf(m, cv[i+d]);
                o[(y0 + i) * W + x] = m;
            }
        }
    }
}

extern "C" void kernel_launch(void* const* d_in, const int* in_sizes, int n_in,
                              void* d_out, int out_size, void* d_ws, size_t ws_size,
                              hipStream_t stream) {
    const float* x = (const float*)d_in[0];
    float* out = (float*)d_out;
    // 16 batches * 256 channels = 4096 images, one block each
    spp_kernel<<<dim3(4096), dim3(TPB), 0, stream>>>(x, out);
}

// Round 2
// 312.146 us; speedup vs baseline: 1.0101x; 1.0101x over previous
//
#include <hip/hip_runtime.h>
#include <math.h>

#define TPB 256
#define W 64
#define H 64
#define LDSW 68   // row stride in floats; breaks pow-2 bank stride, keeps 16B alignment

__global__ __launch_bounds__(TPB) void spp_kernel(const float* __restrict__ in,
                                                  float* __restrict__ out) {
    __shared__ __align__(16) float s_r5[H * LDSW];   // 17,408 B — the ONLY LDS array

    const int tid  = threadIdx.x;
    const int lane = tid & 63;
    const int bc   = blockIdx.x;                 // b*256 + c
    const int b    = bc >> 8;
    const int c    = bc & 255;
    const size_t img   = (size_t)bc * (H * W);
    const size_t obase = ((size_t)b * 1024 + c) * (H * W);
    const size_t pstr  = (size_t)256 * H * W;    // pool stride in out
    const float NEG = -INFINITY;

    // ---- phase 1: coalesced float4 load; pool-0 copy straight to global;
    //      row-max-5 in registers (halo via wave shuffle); write r5 to LDS ----
    {
        const float4* in4 = (const float4*)(in + img);
        float4* o4 = (float4*)(out + obase);
        const int  lm1 = (lane - 1) & 63;
        const int  lp1 = (lane + 1) & 63;
        const bool qlo = (lane & 15) == 0;    // strip starts at x=0  -> left halo is -inf pad
        const bool qhi = (lane & 15) == 15;   // strip ends at x=63   -> right halo is -inf pad
        #pragma unroll
        for (int i = 0; i < 4; ++i) {
            const int idx = tid + TPB * i;    // float4 index 0..1023; lane <-> contiguous float4
            float4 v = in4[idx];
            o4[idx] = v;                      // pool 0 = x, never touches LDS
            // ext window e0..e7 = in[x0-2 .. x0+5] with -inf at image edges
            float e0 = __shfl(v.z, lm1, 64);
            float e1 = __shfl(v.w, lm1, 64);
            float e6 = __shfl(v.x, lp1, 64);
            float e7 = __shfl(v.y, lp1, 64);
            if (qlo) { e0 = NEG; e1 = NEG; }
            if (qhi) { e6 = NEG; e7 = NEG; }
            const float e2 = v.x, e3 = v.y, e4 = v.z, e5 = v.w;
            const float p0 = fmaxf(e0, e1), p1 = fmaxf(e1, e2), p2 = fmaxf(e2, e3);
            const float p3 = fmaxf(e3, e4), p4 = fmaxf(e4, e5), p5 = fmaxf(e5, e6);
            float4 r;                          // r5 at x0..x0+3
            r.x = fmaxf(fmaxf(p0, p2), e4);
            r.y = fmaxf(fmaxf(p1, p3), e5);
            r.z = fmaxf(fmaxf(p2, p4), e6);
            r.w = fmaxf(fmaxf(p3, p5), e7);
            const int y = idx >> 4;
            const int q = idx & 15;
            *(float4*)&s_r5[y * LDSW + 4 * q] = r;
        }
    }
    __syncthreads();   // the ONLY barrier

    // ---- phase 2: column pass. lane = column x (conflict-free LDS reads),
    //      wave w owns rows 16w..16w+15. Horizontal 9/13 widening via clamped
    //      in-wave shuffles of the column maxes (verified == -inf-padded ref). ----
    {
        const int x  = lane;
        const int y0 = (tid >> 6) << 4;
        float cv[28];                          // r5[y0-6 .. y0+21][x], -inf out of range
        #pragma unroll
        for (int j = 0; j < 28; ++j) {
            const int y = y0 - 6 + j;          // wave-uniform bounds check
            cv[j] = (y >= 0 && y < H) ? s_r5[y * LDSW + x] : NEG;
        }
        // shared pairwise-max tree
        float p2a[27], p4a[25], p8a[21];
        #pragma unroll
        for (int j = 0; j < 27; ++j) p2a[j] = fmaxf(cv[j], cv[j + 1]);
        #pragma unroll
        for (int j = 0; j < 25; ++j) p4a[j] = fmaxf(p2a[j], p2a[j + 2]);
        #pragma unroll
        for (int j = 0; j < 21; ++j) p8a[j] = fmaxf(p4a[j], p4a[j + 4]);

        const int xm2 = (x >= 2)  ? x - 2 : 0;
        const int xp2 = (x <= 61) ? x + 2 : 63;
        const int xm4 = (x >= 4)  ? x - 4 : 0;
        const int xp4 = (x <= 59) ? x + 4 : 63;

        float* o5  = out + obase +     pstr + x;
        float* o9  = out + obase + 2 * pstr + x;
        float* o13 = out + obase + 3 * pstr + x;
        #pragma unroll
        for (int i = 0; i < 16; ++i) {
            // column maxes at row y0+i (y-clamping already via -inf cv)
            const float c5  = fmaxf(p4a[i + 4], cv[i + 8]);                     // 5 rows
            const float c9  = fmaxf(p8a[i + 2], cv[i + 10]);                    // 9 rows
            const float c13 = fmaxf(p8a[i], fmaxf(p4a[i + 8], cv[i + 12]));     // 13 rows

            o5[(y0 + i) * W] = c5;

            const float a9 = __shfl(c9, xm2, 64);
            const float b9 = __shfl(c9, xp2, 64);
            o9[(y0 + i) * W] = fmaxf(a9, b9);

            const float a13 = __shfl(c13, xm4, 64);
            const float b13 = __shfl(c13, xp4, 64);
            o13[(y0 + i) * W] = fmaxf(fmaxf(a13, c13), b13);
        }
    }
}

extern "C" void kernel_launch(void* const* d_in, const int* in_sizes, int n_in,
                              void* d_out, int out_size, void* d_ws, size_t ws_size,
                              hipStream_t stream) {
    const float* x = (const float*)d_in[0];
    float* out = (float*)d_out;
    spp_kernel<<<dim3(4096), dim3(TPB), 0, stream>>>(x, out);
}

// Round 3
// 309.714 us; speedup vs baseline: 1.0180x; 1.0079x over previous
//
#include <hip/hip_runtime.h>
#include <math.h>

#define TPB 256
#define W 64
#define H 64
#define LDSW 68   // row stride in floats; breaks pow-2 bank stride, keeps 16B alignment

typedef float f32x4 __attribute__((ext_vector_type(4)));

// ---- P1 tail: pool0 nt-store + in-register row-max-5 (halo via wave shuffle) -> LDS ----
__device__ __forceinline__ void p1_rest(const f32x4 v[4], float* __restrict__ s,
                                        float* __restrict__ outimg, int tid) {
    const int  lane = tid & 63;
    const int  lm1 = (lane - 1) & 63;
    const int  lp1 = (lane + 1) & 63;
    const bool qlo = (lane & 15) == 0;    // strip starts at x=0  -> left halo = -inf
    const bool qhi = (lane & 15) == 15;   // strip ends at x=63   -> right halo = -inf
    const float NEG = -INFINITY;
    f32x4* o4 = (f32x4*)outimg;
    #pragma unroll
    for (int i = 0; i < 4; ++i) {
        const int idx = tid + TPB * i;    // float4 index 0..1023
        f32x4 t = v[i];
        __builtin_nontemporal_store(t, o4 + idx);    // pool 0 = x
        float e0 = __shfl(t.z, lm1, 64);
        float e1 = __shfl(t.w, lm1, 64);
        float e6 = __shfl(t.x, lp1, 64);
        float e7 = __shfl(t.y, lp1, 64);
        if (qlo) { e0 = NEG; e1 = NEG; }
        if (qhi) { e6 = NEG; e7 = NEG; }
        const float e2 = t.x, e3 = t.y, e4 = t.z, e5 = t.w;
        const float p0 = fmaxf(e0, e1), p1 = fmaxf(e1, e2), p2 = fmaxf(e2, e3);
        const float p3 = fmaxf(e3, e4), p4 = fmaxf(e4, e5), p5 = fmaxf(e5, e6);
        f32x4 r;                           // r5 at x0..x0+3
        r.x = fmaxf(fmaxf(p0, p2), e4);
        r.y = fmaxf(fmaxf(p1, p3), e5);
        r.z = fmaxf(fmaxf(p2, p4), e6);
        r.w = fmaxf(fmaxf(p3, p5), e7);
        const int y = idx >> 4;
        const int q = idx & 15;
        *(f32x4*)&s[y * LDSW + 4 * q] = r;
    }
}

// ---- P2: column pass on r5; lane = column x; horizontal 9/13 widening via
//      clamped in-wave shuffles of the column maxes (== -inf-padded reference) ----
__device__ __forceinline__ void p2(const float* __restrict__ s,
                                   float* __restrict__ outimg, int tid) {
    const float NEG = -INFINITY;
    const size_t pstr = (size_t)256 * H * W;
    const int x  = tid & 63;
    const int y0 = (tid >> 6) << 4;
    float cv[28];                          // r5[y0-6 .. y0+21][x], -inf out of range
    #pragma unroll
    for (int j = 0; j < 28; ++j) {
        const int y = y0 - 6 + j;          // wave-uniform bounds check
        cv[j] = (y >= 0 && y < H) ? s[y * LDSW + x] : NEG;
    }
    float p2a[27], p4a[25], p8a[21];
    #pragma unroll
    for (int j = 0; j < 27; ++j) p2a[j] = fmaxf(cv[j], cv[j + 1]);
    #pragma unroll
    for (int j = 0; j < 25; ++j) p4a[j] = fmaxf(p2a[j], p2a[j + 2]);
    #pragma unroll
    for (int j = 0; j < 21; ++j) p8a[j] = fmaxf(p4a[j], p4a[j + 4]);

    const int xm2 = (x >= 2)  ? x - 2 : 0;
    const int xp2 = (x <= 61) ? x + 2 : 63;
    const int xm4 = (x >= 4)  ? x - 4 : 0;
    const int xp4 = (x <= 59) ? x + 4 : 63;

    float* o5  = outimg +     pstr + x;
    float* o9  = outimg + 2 * pstr + x;
    float* o13 = outimg + 3 * pstr + x;
    #pragma unroll
    for (int i = 0; i < 16; ++i) {
        const float c5  = fmaxf(p4a[i + 4], cv[i + 8]);                  // 5 rows
        const float c9  = fmaxf(p8a[i + 2], cv[i + 10]);                 // 9 rows
        const float c13 = fmaxf(p8a[i], fmaxf(p4a[i + 8], cv[i + 12]));  // 13 rows

        __builtin_nontemporal_store(c5, o5 + (y0 + i) * W);

        const float a9 = __shfl(c9, xm2, 64);
        const float b9 = __shfl(c9, xp2, 64);
        __builtin_nontemporal_store(fmaxf(a9, b9), o9 + (y0 + i) * W);

        const float a13 = __shfl(c13, xm4, 64);
        const float b13 = __shfl(c13, xp4, 64);
        __builtin_nontemporal_store(fmaxf(fmaxf(a13, c13), b13), o13 + (y0 + i) * W);
    }
}

__global__ void spp_kernel(const float* __restrict__ in, float* __restrict__ out) {
    __shared__ __align__(16) float s_a[H * LDSW];   // 17,408 B
    __shared__ __align__(16) float s_b[H * LDSW];   // 17,408 B

    const int tid  = threadIdx.x;
    const int imgA = blockIdx.x * 2;
    const int imgB = imgA + 1;
    const size_t obaseA = (((size_t)(imgA >> 8)) * 1024 + (imgA & 255)) * (H * W);
    const size_t obaseB = (((size_t)(imgB >> 8)) * 1024 + (imgB & 255)) * (H * W);

    // ---- stage 1: P1(A) ----
    f32x4 va[4];
    {
        const f32x4* in4 = (const f32x4*)(in + (size_t)imgA * (H * W));
        #pragma unroll
        for (int i = 0; i < 4; ++i) va[i] = __builtin_nontemporal_load(in4 + tid + TPB * i);
    }
    p1_rest(va, s_a, out + obaseA, tid);
    __syncthreads();

    // ---- stage 2: issue B loads first, then P2(A) store burst, then finish P1(B) ----
    f32x4 vb[4];
    {
        const f32x4* in4 = (const f32x4*)(in + (size_t)imgB * (H * W));
        #pragma unroll
        for (int i = 0; i < 4; ++i) vb[i] = __builtin_nontemporal_load(in4 + tid + TPB * i);
    }
    p2(s_a, out + obaseA, tid);
    p1_rest(vb, s_b, out + obaseB, tid);
    __syncthreads();

    // ---- stage 3: P2(B) ----
    p2(s_b, out + obaseB, tid);
}

extern "C" void kernel_launch(void* const* d_in, const int* in_sizes, int n_in,
                              void* d_out, int out_size, void* d_ws, size_t ws_size,
                              hipStream_t stream) {
    const float* x = (const float*)d_in[0];
    float* out = (float*)d_out;
    // 4096 images, 2 per block (software-pipelined), one wave-quad per image
    spp_kernel<<<dim3(2048), dim3(TPB), 0, stream>>>(x, out);
}

// Round 4
// 308.903 us; speedup vs baseline: 1.0207x; 1.0026x over previous
//
#include <hip/hip_runtime.h>
#include <math.h>

#define TPB 256
#define W 64
#define H 64
#define LDSW 68   // r5 row stride in floats; breaks pow-2 bank stride, keeps 16B alignment

typedef float f32x4 __attribute__((ext_vector_type(4)));

__device__ __forceinline__ f32x4 max4(f32x4 a, f32x4 b) {
    f32x4 r;
    r.x = fmaxf(a.x, b.x); r.y = fmaxf(a.y, b.y);
    r.z = fmaxf(a.z, b.z); r.w = fmaxf(a.w, b.w);
    return r;
}

// ---- P1: pool0 nt-store + in-register row-max-5 (halo via wave shuffle) -> LDS ----
__device__ __forceinline__ void p1_rest(const f32x4 v[4], float* __restrict__ s,
                                        float* __restrict__ outimg, int tid) {
    const int  lane = tid & 63;
    const int  lm1 = (lane - 1) & 63;
    const int  lp1 = (lane + 1) & 63;
    const bool qlo = (lane & 15) == 0;    // strip starts at x=0  -> left halo = -inf
    const bool qhi = (lane & 15) == 15;   // strip ends at x=63   -> right halo = -inf
    const float NEG = -INFINITY;
    f32x4* o4 = (f32x4*)outimg;
    #pragma unroll
    for (int i = 0; i < 4; ++i) {
        const int idx = tid + TPB * i;    // float4 index 0..1023
        f32x4 t = v[i];
        __builtin_nontemporal_store(t, o4 + idx);    // pool 0 = x
        float e0 = __shfl(t.z, lm1, 64);
        float e1 = __shfl(t.w, lm1, 64);
        float e6 = __shfl(t.x, lp1, 64);
        float e7 = __shfl(t.y, lp1, 64);
        if (qlo) { e0 = NEG; e1 = NEG; }
        if (qhi) { e6 = NEG; e7 = NEG; }
        const float e2 = t.x, e3 = t.y, e4 = t.z, e5 = t.w;
        const float p0 = fmaxf(e0, e1), p1 = fmaxf(e1, e2), p2 = fmaxf(e2, e3);
        const float p3 = fmaxf(e3, e4), p4 = fmaxf(e4, e5), p5 = fmaxf(e5, e6);
        f32x4 r;                           // r5 at x0..x0+3
        r.x = fmaxf(fmaxf(p0, p2), e4);
        r.y = fmaxf(fmaxf(p1, p3), e5);
        r.z = fmaxf(fmaxf(p2, p4), e6);
        r.w = fmaxf(fmaxf(p3, p5), e7);
        const int y = idx >> 4;
        const int q = idx & 15;
        *(f32x4*)&s[y * LDSW + 4 * q] = r;
    }
}

// ---- P2: column pass on r5, thread owns a 4-wide x 4-tall tile.
//      ds_read_b128 in, float4 vertical max tree, lane+-1 shuffles for the
//      horizontal 9/13 widening, global_store_dwordx4 out for ALL pools. ----
__device__ __forceinline__ void p2(const float* __restrict__ s,
                                   float* __restrict__ outimg, int tid) {
    const float NEG = -INFINITY;
    const size_t pstr = (size_t)256 * H * W;
    const int g    = tid & 15;            // col group: x = 4g..4g+3
    const int x0   = g << 2;
    const int y0   = (tid >> 4) << 2;     // row group: y = y0..y0+3
    const int lane = tid & 63;
    const int lm1  = (lane - 1) & 63;     // left neighbor col-group (same rows)
    const int lp1  = (lane + 1) & 63;     // right neighbor col-group
    const bool qlo = (g == 0);
    const bool qhi = (g == 15);

    f32x4 cv[16];                          // r5[y0-6 .. y0+9][x0..x0+3], -inf out of range
    #pragma unroll
    for (int j = 0; j < 16; ++j) {
        const int y  = y0 - 6 + j;
        const int yc = y < 0 ? 0 : (y > 63 ? 63 : y);
        f32x4 v = *(const f32x4*)&s[yc * LDSW + x0];
        if (y < 0 || y > 63) v = (f32x4){NEG, NEG, NEG, NEG};
        cv[j] = v;
    }
    // shared pairwise-max tree (vertical)
    f32x4 m2[15], m4[13], m8[9];
    #pragma unroll
    for (int j = 0; j < 15; ++j) m2[j] = max4(cv[j], cv[j + 1]);
    #pragma unroll
    for (int j = 0; j < 13; ++j) m4[j] = max4(m2[j], m2[j + 2]);
    #pragma unroll
    for (int j = 0; j < 9;  ++j) m8[j] = max4(m4[j], m4[j + 4]);

    float* o5  = outimg +     pstr;
    float* o9  = outimg + 2 * pstr;
    float* o13 = outimg + 3 * pstr;
    #pragma unroll
    for (int i = 0; i < 4; ++i) {
        // column maxes (windows 5/9/13 rows) at output row y0+i, cols x0..x0+3
        const f32x4 c5  = max4(m4[i + 4], cv[i + 8]);
        const f32x4 c9  = max4(m8[i + 2], cv[i + 10]);
        const f32x4 c13 = max4(max4(m8[i], m4[i + 8]), cv[i + 12]);

        __builtin_nontemporal_store(c5, (f32x4*)(o5 + (y0 + i) * W + x0));

        // pool9: out[x] = max(c9[clamp(x-2)], c9[clamp(x+2)])
        const float Lz = __shfl(c9.z, lm1, 64);
        const float Lw = __shfl(c9.w, lm1, 64);
        const float Rx = __shfl(c9.x, lp1, 64);
        const float Ry = __shfl(c9.y, lp1, 64);
        const f32x4 lh9 = qlo ? (f32x4){c9.x, c9.x, c9.x, c9.y}
                              : (f32x4){Lz, Lw, c9.x, c9.y};
        const f32x4 rh9 = qhi ? (f32x4){c9.z, c9.w, c9.w, c9.w}
                              : (f32x4){c9.z, c9.w, Rx, Ry};
        __builtin_nontemporal_store(max4(lh9, rh9), (f32x4*)(o9 + (y0 + i) * W + x0));

        // pool13: out[x] = max(c13[clamp(x-4)], c13[x], c13[clamp(x+4)])
        f32x4 L13, R13;
        L13.x = __shfl(c13.x, lm1, 64); L13.y = __shfl(c13.y, lm1, 64);
        L13.z = __shfl(c13.z, lm1, 64); L13.w = __shfl(c13.w, lm1, 64);
        R13.x = __shfl(c13.x, lp1, 64); R13.y = __shfl(c13.y, lp1, 64);
        R13.z = __shfl(c13.z, lp1, 64); R13.w = __shfl(c13.w, lp1, 64);
        const f32x4 lh13 = qlo ? (f32x4){c13.x, c13.x, c13.x, c13.x} : L13;
        const f32x4 rh13 = qhi ? (f32x4){c13.w, c13.w, c13.w, c13.w} : R13;
        __builtin_nontemporal_store(max4(max4(lh13, c13), rh13),
                                    (f32x4*)(o13 + (y0 + i) * W + x0));
    }
}

__global__ __launch_bounds__(TPB, 2) void spp_kernel(const float* __restrict__ in,
                                                     float* __restrict__ out) {
    __shared__ __align__(16) float s_a[H * LDSW];   // 17,408 B
    __shared__ __align__(16) float s_b[H * LDSW];   // 17,408 B

    const int tid  = threadIdx.x;
    const int imgA = blockIdx.x * 2;
    const int imgB = imgA + 1;
    const size_t obaseA = (((size_t)(imgA >> 8)) * 1024 + (imgA & 255)) * (H * W);
    const size_t obaseB = (((size_t)(imgB >> 8)) * 1024 + (imgB & 255)) * (H * W);

    // ---- stage 1: P1(A) ----
    f32x4 va[4];
    {
        const f32x4* in4 = (const f32x4*)(in + (size_t)imgA * (H * W));
        #pragma unroll
        for (int i = 0; i < 4; ++i) va[i] = __builtin_nontemporal_load(in4 + tid + TPB * i);
    }
    p1_rest(va, s_a, out + obaseA, tid);
    __syncthreads();

    // ---- stage 2: issue B loads first, then P2(A) store burst, then finish P1(B) ----
    f32x4 vb[4];
    {
        const f32x4* in4 = (const f32x4*)(in + (size_t)imgB * (H * W));
        #pragma unroll
        for (int i = 0; i < 4; ++i) vb[i] = __builtin_nontemporal_load(in4 + tid + TPB * i);
    }
    p2(s_a, out + obaseA, tid);
    p1_rest(vb, s_b, out + obaseB, tid);
    __syncthreads();

    // ---- stage 3: P2(B) ----
    p2(s_b, out + obaseB, tid);
}

extern "C" void kernel_launch(void* const* d_in, const int* in_sizes, int n_in,
                              void* d_out, int out_size, void* d_ws, size_t ws_size,
                              hipStream_t stream) {
    const float* x = (const float*)d_in[0];
    float* out = (float*)d_out;
    // 4096 images, 2 per block (software-pipelined), all-dwordx4 output path
    spp_kernel<<<dim3(2048), dim3(TPB), 0, stream>>>(x, out);
}